// Round 1
// baseline (1886.160 us; speedup 1.0000x reference)
//
#include <hip/hip_runtime.h>
#include <math.h>

#define NNODES 15840
#define NEDGES 253440
#define INCH 128
#define HIDC 256
#define BGR 48
#define GNODES 330

// ---------------- LayerNorm: one wave per node row (128 feats, 2/lane) ----------------
__global__ void ln_kernel(const float* __restrict__ x, const float* __restrict__ g,
                          const float* __restrict__ b, float* __restrict__ xln) {
  int wid = (blockIdx.x * blockDim.x + threadIdx.x) >> 6;
  int lane = threadIdx.x & 63;
  if (wid >= NNODES) return;
  float2 v = *(const float2*)(x + (size_t)wid * INCH + lane * 2);
  float s = v.x + v.y;
#pragma unroll
  for (int o = 32; o > 0; o >>= 1) s += __shfl_xor(s, o);
  float mean = s * (1.0f / INCH);
  float d0 = v.x - mean, d1 = v.y - mean;
  float sq = d0 * d0 + d1 * d1;
#pragma unroll
  for (int o = 32; o > 0; o >>= 1) sq += __shfl_xor(sq, o);
  float rstd = rsqrtf(sq * (1.0f / INCH) + 1e-5f);
  float2 gg = *(const float2*)(g + lane * 2);
  float2 bb = *(const float2*)(b + lane * 2);
  float2 o2;
  o2.x = d0 * rstd * gg.x + bb.x;
  o2.y = d1 * rstd * gg.y + bb.y;
  *(float2*)(xln + (size_t)wid * INCH + lane * 2) = o2;
}

// ---------------- Q,K,V,Skip GEMMs fused: one block per node ----------------
__global__ void qkvs_kernel(const float* __restrict__ xln,
                            const float* __restrict__ Wq, const float* __restrict__ bq,
                            const float* __restrict__ Wk, const float* __restrict__ bk,
                            const float* __restrict__ Wv, const float* __restrict__ bv,
                            const float* __restrict__ Ws, const float* __restrict__ bs,
                            float* __restrict__ QKVS) {
  __shared__ float xs[INCH];
  int n = blockIdx.x, t = threadIdx.x;
  if (t < INCH) xs[t] = xln[(size_t)n * INCH + t];
  __syncthreads();
  const float4* xv = (const float4*)xs;
  const float4* wq = (const float4*)(Wq + t * INCH);
  const float4* wk = (const float4*)(Wk + t * INCH);
  const float4* wv = (const float4*)(Wv + t * INCH);
  const float4* wsk = (const float4*)(Ws + t * INCH);
  float a0 = bq[t], a1 = bk[t], a2 = bv[t], a3 = bs[t];
#pragma unroll 8
  for (int i = 0; i < INCH / 4; i++) {
    float4 xi = xv[i];
    float4 w;
    w = wq[i];  a0 += xi.x * w.x + xi.y * w.y + xi.z * w.z + xi.w * w.w;
    w = wk[i];  a1 += xi.x * w.x + xi.y * w.y + xi.z * w.z + xi.w * w.w;
    w = wv[i];  a2 += xi.x * w.x + xi.y * w.y + xi.z * w.z + xi.w * w.w;
    w = wsk[i]; a3 += xi.x * w.x + xi.y * w.y + xi.z * w.z + xi.w * w.w;
  }
  float* o = QKVS + (size_t)n * 1024;
  o[t] = a0; o[256 + t] = a1; o[512 + t] = a2; o[768 + t] = a3;
}

// ---------------- CSR build ----------------
__global__ void count_kernel(const int* __restrict__ dst, int* __restrict__ deg) {
  int e = blockIdx.x * blockDim.x + threadIdx.x;
  if (e < NEDGES) atomicAdd(&deg[dst[e]], 1);
}

__global__ void scan_kernel(const int* __restrict__ deg, int* __restrict__ row_start) {
  __shared__ int buf[256];
  __shared__ int carry;
  int t = threadIdx.x;
  if (t == 0) carry = 0;
  __syncthreads();
  for (int base = 0; base < NNODES; base += 256) {
    int i = base + t;
    int v = (i < NNODES) ? deg[i] : 0;
    buf[t] = v;
    __syncthreads();
#pragma unroll
    for (int off = 1; off < 256; off <<= 1) {
      int add = (t >= off) ? buf[t - off] : 0;
      __syncthreads();
      buf[t] += add;
      __syncthreads();
    }
    int incl = buf[t];
    int cl = carry;
    if (i < NNODES) row_start[i] = cl + incl - v;
    __syncthreads();
    if (t == 255) carry = cl + incl;
    __syncthreads();
  }
  if (t == 0) row_start[NNODES] = carry;
}

__global__ void scatter_kernel(const int* __restrict__ dst, const int* __restrict__ row_start,
                               int* __restrict__ cursor, int* __restrict__ elist) {
  int e = blockIdx.x * blockDim.x + threadIdx.x;
  if (e < NEDGES) {
    int d = dst[e];
    int pos = atomicAdd(&cursor[d], 1);
    elist[row_start[d] + pos] = e;
  }
}

// ---------------- Attention aggregation: one wave per dst node, online softmax ----------------
__global__ void agg_kernel(const float* __restrict__ QKVS, const float* __restrict__ edge_attr,
                           const float* __restrict__ We, const int* __restrict__ srcArr,
                           const int* __restrict__ row_start, const int* __restrict__ elist,
                           float* __restrict__ outb) {
  __shared__ float we_s[HIDC * 5];
  int t = threadIdx.x;
#pragma unroll
  for (int d = 0; d < 5; d++) we_s[t * 5 + d] = We[t * 5 + d];
  __syncthreads();

  int nd = blockIdx.x * 4 + (t >> 6);
  int lane = t & 63;
  if (nd >= NNODES) return;

  const float* qp = QKVS + (size_t)nd * 1024 + 4 * lane;
  float4 q = *(const float4*)qp;
  int beg = row_start[nd], end = row_start[nd + 1];

  float m = -INFINITY, z = 0.0f;
  float ax = 0.0f, ay = 0.0f, az = 0.0f, aw = 0.0f;
  const float* wp = we_s + (4 * lane) * 5;

  for (int j = beg; j < end; j++) {
    int e = elist[j];
    int s = srcArr[e];
    const float* eap = edge_attr + (size_t)e * 5;
    float e0 = eap[0], e1 = eap[1], e2 = eap[2], e3 = eap[3], e4 = eap[4];
    float efx = e0 * wp[0]  + e1 * wp[1]  + e2 * wp[2]  + e3 * wp[3]  + e4 * wp[4];
    float efy = e0 * wp[5]  + e1 * wp[6]  + e2 * wp[7]  + e3 * wp[8]  + e4 * wp[9];
    float efz = e0 * wp[10] + e1 * wp[11] + e2 * wp[12] + e3 * wp[13] + e4 * wp[14];
    float efw = e0 * wp[15] + e1 * wp[16] + e2 * wp[17] + e3 * wp[18] + e4 * wp[19];

    const float* kp = QKVS + (size_t)s * 1024 + 256 + 4 * lane;
    const float* vp = QKVS + (size_t)s * 1024 + 512 + 4 * lane;
    float4 k4 = *(const float4*)kp;
    float4 v4 = *(const float4*)vp;

    float part = q.x * (k4.x + efx) + q.y * (k4.y + efy) +
                 q.z * (k4.z + efz) + q.w * (k4.w + efw);
#pragma unroll
    for (int o = 32; o > 0; o >>= 1) part += __shfl_xor(part, o);
    float alpha = part * 0.0625f;  // 1/sqrt(256)

    float nm = fmaxf(m, alpha);
    float scale = __expf(m - nm);   // exp(-inf)=0 on first edge
    float p = __expf(alpha - nm);
    z = z * scale + p;
    ax = ax * scale + p * (v4.x + efx);
    ay = ay * scale + p * (v4.y + efy);
    az = az * scale + p * (v4.z + efz);
    aw = aw * scale + p * (v4.w + efw);
    m = nm;
  }

  float inv = 1.0f / (z + 1e-16f);
  const float* skp = QKVS + (size_t)nd * 1024 + 768 + 4 * lane;
  float4 sk = *(const float4*)skp;
  float4 o;
  o.x = ax * inv + sk.x;
  o.y = ay * inv + sk.y;
  o.z = az * inv + sk.z;
  o.w = aw * inv + sk.w;
  *(float4*)(outb + (size_t)nd * HIDC + 4 * lane) = o;
}

// ---------------- BatchNorm statistics ----------------
__global__ void bnstat_kernel(const float* __restrict__ outb, float* __restrict__ sums,
                              float* __restrict__ sumsq) {
  int f = threadIdx.x;
  int r0 = blockIdx.x * 120;
  float s = 0.0f, sq = 0.0f;
  for (int r = 0; r < 120; r++) {
    float v = outb[(size_t)(r0 + r) * HIDC + f];
    s += v; sq += v * v;
  }
  atomicAdd(&sums[f], s);
  atomicAdd(&sumsq[f], sq);
}

// ---------------- BN-apply + ReLU + max-pool chain (18 consecutive nodes) ----------------
__global__ void pool_kernel(const float* __restrict__ outb, const float* __restrict__ sums,
                            const float* __restrict__ sumsq, const float* __restrict__ bng,
                            const float* __restrict__ bnb, float* __restrict__ h) {
  int bt = blockIdx.x;     // b*18 + t
  int f = threadIdx.x;
  int b = bt / 18, tt = bt % 18;
  float mean = sums[f] * (1.0f / NNODES);
  float var = sumsq[f] * (1.0f / NNODES) - mean * mean;
  float scale = bng[f] * rsqrtf(var + 1e-5f);
  float shift = bnb[f] - mean * scale;
  int base = b * GNODES + tt * 18;
  float mx = -INFINITY;
  for (int r = 0; r < 18; r++) {
    float v = outb[(size_t)(base + r) * HIDC + f];
    v = fmaxf(v * scale + shift, 0.0f);
    mx = fmaxf(mx, v);
  }
  h[(size_t)bt * HIDC + f] = mx;
}

// ---------------- MLP head: relu(h@W1^T+b1) @ Wr^T, mean over 18 ----------------
__global__ void mlp_kernel(const float* __restrict__ h, const float* __restrict__ W1,
                           const float* __restrict__ b1, const float* __restrict__ Wr,
                           float* __restrict__ c) {
  __shared__ float hs[HIDC];
  __shared__ float red[HIDC];
  int bt = blockIdx.x, t = threadIdx.x;
  hs[t] = h[(size_t)bt * HIDC + t];
  __syncthreads();
  const float4* hv = (const float4*)hs;
  const float4* w = (const float4*)(W1 + t * HIDC);
  float acc = b1[t];
#pragma unroll 8
  for (int i = 0; i < HIDC / 4; i++) {
    float4 xi = hv[i]; float4 ww = w[i];
    acc += xi.x * ww.x + xi.y * ww.y + xi.z * ww.z + xi.w * ww.w;
  }
  red[t] = fmaxf(acc, 0.0f) * Wr[t];
  __syncthreads();
#pragma unroll
  for (int s = 128; s > 0; s >>= 1) {
    if (t < s) red[t] += red[t + s];
    __syncthreads();
  }
  if (t == 0) atomicAdd(&c[bt / 18], red[0] * (1.0f / 18.0f));
}

__global__ void final_kernel(const float* __restrict__ c, const float* __restrict__ br,
                             float* __restrict__ out) {
  int b = threadIdx.x;
  if (b < BGR) out[b] = 1.0f / (1.0f + expf(-(c[b] + br[0])));
}

extern "C" void kernel_launch(void* const* d_in, const int* in_sizes, int n_in,
                              void* d_out, int out_size, void* d_ws, size_t ws_size,
                              hipStream_t stream) {
  const float* x   = (const float*)d_in[0];
  const int*   ei  = (const int*)d_in[1];
  const float* ea  = (const float*)d_in[2];
  const float* Wq  = (const float*)d_in[4];  const float* bq  = (const float*)d_in[5];
  const float* Wk  = (const float*)d_in[6];  const float* bk  = (const float*)d_in[7];
  const float* Wv  = (const float*)d_in[8];  const float* bv  = (const float*)d_in[9];
  const float* We  = (const float*)d_in[10];
  const float* Wsk = (const float*)d_in[11]; const float* bsk = (const float*)d_in[12];
  const float* lng = (const float*)d_in[13]; const float* lnb = (const float*)d_in[14];
  const float* bng = (const float*)d_in[15]; const float* bnb = (const float*)d_in[16];
  const float* W1  = (const float*)d_in[17]; const float* b1  = (const float*)d_in[18];
  const float* Wr  = (const float*)d_in[19]; const float* br  = (const float*)d_in[20];
  float* outp = (float*)d_out;

  const int* srcArr = ei;
  const int* dstArr = ei + NEDGES;

  char* ws = (char*)d_ws;
  size_t off = 0;
  auto alloc = [&](size_t bytes) -> void* {
    void* p = ws + off;
    off += (bytes + 255) & ~(size_t)255;
    return p;
  };
  float* xln       = (float*)alloc((size_t)NNODES * INCH * 4);
  float* QKVS      = (float*)alloc((size_t)NNODES * 1024 * 4);
  float* outb      = (float*)alloc((size_t)NNODES * HIDC * 4);
  float* hbuf      = (float*)alloc((size_t)BGR * 18 * HIDC * 4);
  int*   row_start = (int*)alloc((size_t)(NNODES + 1) * 4);
  int*   elist     = (int*)alloc((size_t)NEDGES * 4);
  int*   deg       = (int*)alloc((size_t)NNODES * 4);
  int*   cursor    = (int*)alloc((size_t)NNODES * 4);
  float* sums      = (float*)alloc(HIDC * 4);
  float* sumsq     = (float*)alloc(HIDC * 4);
  float* cacc      = (float*)alloc(BGR * 4);

  // zero accumulators (workspace is poisoned with 0xAA before every launch)
  hipMemsetAsync(deg,    0, (size_t)NNODES * 4, stream);
  hipMemsetAsync(cursor, 0, (size_t)NNODES * 4, stream);
  hipMemsetAsync(sums,   0, HIDC * 4, stream);
  hipMemsetAsync(sumsq,  0, HIDC * 4, stream);
  hipMemsetAsync(cacc,   0, BGR * 4, stream);

  ln_kernel<<<NNODES / 4, 256, 0, stream>>>(x, lng, lnb, xln);
  qkvs_kernel<<<NNODES, 256, 0, stream>>>(xln, Wq, bq, Wk, bk, Wv, bv, Wsk, bsk, QKVS);
  count_kernel<<<NEDGES / 256, 256, 0, stream>>>(dstArr, deg);
  scan_kernel<<<1, 256, 0, stream>>>(deg, row_start);
  scatter_kernel<<<NEDGES / 256, 256, 0, stream>>>(dstArr, row_start, cursor, elist);
  agg_kernel<<<NNODES / 4, 256, 0, stream>>>(QKVS, ea, We, srcArr, row_start, elist, outb);
  bnstat_kernel<<<132, 256, 0, stream>>>(outb, sums, sumsq);
  pool_kernel<<<BGR * 18, 256, 0, stream>>>(outb, sums, sumsq, bng, bnb, hbuf);
  mlp_kernel<<<BGR * 18, 256, 0, stream>>>(hbuf, W1, b1, Wr, cacc);
  final_kernel<<<1, 64, 0, stream>>>(cacc, br, outp);
}

// Round 2
// 415.263 us; speedup vs baseline: 4.5421x; 4.5421x over previous
//
#include <hip/hip_runtime.h>
#include <math.h>

#define NNODES 15840
#define NEDGES 253440
#define INCH 128
#define HIDC 256
#define BGR 48
#define GNODES 330

// ---------------- LayerNorm: one wave per node row (128 feats, 2/lane) ----------------
__global__ void ln_kernel(const float* __restrict__ x, const float* __restrict__ g,
                          const float* __restrict__ b, float* __restrict__ xln) {
  int wid = (blockIdx.x * blockDim.x + threadIdx.x) >> 6;
  int lane = threadIdx.x & 63;
  if (wid >= NNODES) return;
  float2 v = *(const float2*)(x + (size_t)wid * INCH + lane * 2);
  float s = v.x + v.y;
#pragma unroll
  for (int o = 32; o > 0; o >>= 1) s += __shfl_xor(s, o);
  float mean = s * (1.0f / INCH);
  float d0 = v.x - mean, d1 = v.y - mean;
  float sq = d0 * d0 + d1 * d1;
#pragma unroll
  for (int o = 32; o > 0; o >>= 1) sq += __shfl_xor(sq, o);
  float rstd = rsqrtf(sq * (1.0f / INCH) + 1e-5f);
  float2 gg = *(const float2*)(g + lane * 2);
  float2 bb = *(const float2*)(b + lane * 2);
  float2 o2;
  o2.x = d0 * rstd * gg.x + bb.x;
  o2.y = d1 * rstd * gg.y + bb.y;
  *(float2*)(xln + (size_t)wid * INCH + lane * 2) = o2;
}

// ---------------- Q,K,V,Skip as one tiled SGEMM: C[15840 x 1024] = X[15840x128] * W^T ----
// Block: 64 rows (nodes) x 64 cols (features of one of the 4 matrices).
// LDS: As[k][m] 64x128, Bs[k][j] 64x128 (both transposed to K-major). No K tiling (K=128).
#define BM 64
#define BN 64
#define KD 128
__global__ __launch_bounds__(256, 2) void gemm_qkvs(
    const float* __restrict__ xln,
    const float* __restrict__ Wq, const float* __restrict__ bq,
    const float* __restrict__ Wk, const float* __restrict__ bk,
    const float* __restrict__ Wv, const float* __restrict__ bv,
    const float* __restrict__ Ws, const float* __restrict__ bs,
    float* __restrict__ QKVS) {
  __shared__ float As[KD][BM];
  __shared__ float Bs[KD][BN];
  int t = threadIdx.x;
  int m0 = blockIdx.x * BM;
  int jb = blockIdx.y;            // 0..15 -> global col block
  int j0 = (jb & 3) * BN;         // row offset inside the selected weight matrix
  const float* W; const float* bias;
  switch (jb >> 2) {
    case 0:  W = Wq; bias = bq; break;
    case 1:  W = Wk; bias = bk; break;
    case 2:  W = Wv; bias = bv; break;
    default: W = Ws; bias = bs; break;
  }

  // Stage A (64 node-rows x 128 k) transposed into As[k][row].
  // thread t: row = t&63, k-chunk = (t>>6)*32 .. +32 (8 float4 per thread).
  {
    int row = t & 63;
    int c0 = (t >> 6) * 32;
    int gr = m0 + row;
    bool ok = gr < NNODES;
    const float4* src = (const float4*)(xln + (size_t)gr * KD + c0);
#pragma unroll
    for (int i = 0; i < 8; i++) {
      float4 v = ok ? src[i] : make_float4(0.f, 0.f, 0.f, 0.f);
      int k = c0 + i * 4;
      As[k + 0][row] = v.x; As[k + 1][row] = v.y;
      As[k + 2][row] = v.z; As[k + 3][row] = v.w;
    }
  }
  // Stage B (64 weight-rows x 128 k) transposed into Bs[k][j].
  {
    int row = t & 63;
    int c0 = (t >> 6) * 32;
    const float4* src = (const float4*)(W + (size_t)(j0 + row) * KD + c0);
#pragma unroll
    for (int i = 0; i < 8; i++) {
      float4 v = src[i];
      int k = c0 + i * 4;
      Bs[k + 0][row] = v.x; Bs[k + 1][row] = v.y;
      Bs[k + 2][row] = v.z; Bs[k + 3][row] = v.w;
    }
  }
  __syncthreads();

  int tx = t & 15, ty = t >> 4;   // 16x16 thread grid, 4x4 micro-tile each
  float acc[4][4] = {};
#pragma unroll 8
  for (int k = 0; k < KD; k++) {
    float4 a = *(const float4*)&As[k][ty * 4];
    float4 b = *(const float4*)&Bs[k][tx * 4];
    acc[0][0] += a.x * b.x; acc[0][1] += a.x * b.y; acc[0][2] += a.x * b.z; acc[0][3] += a.x * b.w;
    acc[1][0] += a.y * b.x; acc[1][1] += a.y * b.y; acc[1][2] += a.y * b.z; acc[1][3] += a.y * b.w;
    acc[2][0] += a.z * b.x; acc[2][1] += a.z * b.y; acc[2][2] += a.z * b.z; acc[2][3] += a.z * b.w;
    acc[3][0] += a.w * b.x; acc[3][1] += a.w * b.y; acc[3][2] += a.w * b.z; acc[3][3] += a.w * b.w;
  }

  float4 bb = *(const float4*)(bias + j0 + tx * 4);
  int jcol = jb * BN + tx * 4;    // global col in [0,1024)
#pragma unroll
  for (int r = 0; r < 4; r++) {
    int gr = m0 + ty * 4 + r;
    if (gr < NNODES) {
      float4 o;
      o.x = acc[r][0] + bb.x; o.y = acc[r][1] + bb.y;
      o.z = acc[r][2] + bb.z; o.w = acc[r][3] + bb.w;
      *(float4*)(QKVS + (size_t)gr * 1024 + jcol) = o;
    }
  }
}

// ---------------- CSR build ----------------
__global__ void count_kernel(const int* __restrict__ dst, int* __restrict__ deg) {
  int e = blockIdx.x * blockDim.x + threadIdx.x;
  if (e < NEDGES) atomicAdd(&deg[dst[e]], 1);
}

__global__ void scan_kernel(const int* __restrict__ deg, int* __restrict__ row_start) {
  __shared__ int buf[256];
  __shared__ int carry;
  int t = threadIdx.x;
  if (t == 0) carry = 0;
  __syncthreads();
  for (int base = 0; base < NNODES; base += 256) {
    int i = base + t;
    int v = (i < NNODES) ? deg[i] : 0;
    buf[t] = v;
    __syncthreads();
#pragma unroll
    for (int off = 1; off < 256; off <<= 1) {
      int add = (t >= off) ? buf[t - off] : 0;
      __syncthreads();
      buf[t] += add;
      __syncthreads();
    }
    int incl = buf[t];
    int cl = carry;
    if (i < NNODES) row_start[i] = cl + incl - v;
    __syncthreads();
    if (t == 255) carry = cl + incl;
    __syncthreads();
  }
  if (t == 0) row_start[NNODES] = carry;
}

__global__ void scatter_kernel(const int* __restrict__ dst, const int* __restrict__ row_start,
                               int* __restrict__ cursor, int* __restrict__ elist) {
  int e = blockIdx.x * blockDim.x + threadIdx.x;
  if (e < NEDGES) {
    int d = dst[e];
    int pos = atomicAdd(&cursor[d], 1);
    elist[row_start[d] + pos] = e;
  }
}

// ---------------- Attention aggregation: one wave per dst node, online softmax ----------------
__global__ void agg_kernel(const float* __restrict__ QKVS, const float* __restrict__ edge_attr,
                           const float* __restrict__ We, const int* __restrict__ srcArr,
                           const int* __restrict__ row_start, const int* __restrict__ elist,
                           float* __restrict__ outb) {
  __shared__ float we_s[HIDC * 5];
  int t = threadIdx.x;
#pragma unroll
  for (int d = 0; d < 5; d++) we_s[t * 5 + d] = We[t * 5 + d];
  __syncthreads();

  int nd = blockIdx.x * 4 + (t >> 6);
  int lane = t & 63;
  if (nd >= NNODES) return;

  const float* qp = QKVS + (size_t)nd * 1024 + 4 * lane;
  float4 q = *(const float4*)qp;
  int beg = row_start[nd], end = row_start[nd + 1];

  float m = -INFINITY, z = 0.0f;
  float ax = 0.0f, ay = 0.0f, az = 0.0f, aw = 0.0f;
  const float* wp = we_s + (4 * lane) * 5;

  for (int j = beg; j < end; j++) {
    int e = elist[j];
    int s = srcArr[e];
    const float* eap = edge_attr + (size_t)e * 5;
    float e0 = eap[0], e1 = eap[1], e2 = eap[2], e3 = eap[3], e4 = eap[4];
    float efx = e0 * wp[0]  + e1 * wp[1]  + e2 * wp[2]  + e3 * wp[3]  + e4 * wp[4];
    float efy = e0 * wp[5]  + e1 * wp[6]  + e2 * wp[7]  + e3 * wp[8]  + e4 * wp[9];
    float efz = e0 * wp[10] + e1 * wp[11] + e2 * wp[12] + e3 * wp[13] + e4 * wp[14];
    float efw = e0 * wp[15] + e1 * wp[16] + e2 * wp[17] + e3 * wp[18] + e4 * wp[19];

    const float* kp = QKVS + (size_t)s * 1024 + 256 + 4 * lane;
    const float* vp = QKVS + (size_t)s * 1024 + 512 + 4 * lane;
    float4 k4 = *(const float4*)kp;
    float4 v4 = *(const float4*)vp;

    float part = q.x * (k4.x + efx) + q.y * (k4.y + efy) +
                 q.z * (k4.z + efz) + q.w * (k4.w + efw);
#pragma unroll
    for (int o = 32; o > 0; o >>= 1) part += __shfl_xor(part, o);
    float alpha = part * 0.0625f;  // 1/sqrt(256)

    float nm = fmaxf(m, alpha);
    float scale = __expf(m - nm);   // exp(-inf)=0 on first edge
    float p = __expf(alpha - nm);
    z = z * scale + p;
    ax = ax * scale + p * (v4.x + efx);
    ay = ay * scale + p * (v4.y + efy);
    az = az * scale + p * (v4.z + efz);
    aw = aw * scale + p * (v4.w + efw);
    m = nm;
  }

  float inv = 1.0f / (z + 1e-16f);
  const float* skp = QKVS + (size_t)nd * 1024 + 768 + 4 * lane;
  float4 sk = *(const float4*)skp;
  float4 o;
  o.x = ax * inv + sk.x;
  o.y = ay * inv + sk.y;
  o.z = az * inv + sk.z;
  o.w = aw * inv + sk.w;
  *(float4*)(outb + (size_t)nd * HIDC + 4 * lane) = o;
}

// ---------------- BatchNorm statistics ----------------
__global__ void bnstat_kernel(const float* __restrict__ outb, float* __restrict__ sums,
                              float* __restrict__ sumsq) {
  int f = threadIdx.x;
  int r0 = blockIdx.x * 120;
  float s = 0.0f, sq = 0.0f;
  for (int r = 0; r < 120; r++) {
    float v = outb[(size_t)(r0 + r) * HIDC + f];
    s += v; sq += v * v;
  }
  atomicAdd(&sums[f], s);
  atomicAdd(&sumsq[f], sq);
}

// ---------------- BN-apply + ReLU + max-pool chain (18 consecutive nodes) ----------------
__global__ void pool_kernel(const float* __restrict__ outb, const float* __restrict__ sums,
                            const float* __restrict__ sumsq, const float* __restrict__ bng,
                            const float* __restrict__ bnb, float* __restrict__ h) {
  int bt = blockIdx.x;     // b*18 + t
  int f = threadIdx.x;
  int b = bt / 18, tt = bt % 18;
  float mean = sums[f] * (1.0f / NNODES);
  float var = sumsq[f] * (1.0f / NNODES) - mean * mean;
  float scale = bng[f] * rsqrtf(var + 1e-5f);
  float shift = bnb[f] - mean * scale;
  int base = b * GNODES + tt * 18;
  float mx = -INFINITY;
  for (int r = 0; r < 18; r++) {
    float v = outb[(size_t)(base + r) * HIDC + f];
    v = fmaxf(v * scale + shift, 0.0f);
    mx = fmaxf(mx, v);
  }
  h[(size_t)bt * HIDC + f] = mx;
}

// ---------------- MLP head: relu(h@W1^T+b1) @ Wr^T, mean over 18 ----------------
__global__ void mlp_kernel(const float* __restrict__ h, const float* __restrict__ W1,
                           const float* __restrict__ b1, const float* __restrict__ Wr,
                           float* __restrict__ c) {
  __shared__ float hs[HIDC];
  __shared__ float red[HIDC];
  int bt = blockIdx.x, t = threadIdx.x;
  hs[t] = h[(size_t)bt * HIDC + t];
  __syncthreads();
  const float4* hv = (const float4*)hs;
  const float4* w = (const float4*)(W1 + t * HIDC);
  float acc = b1[t];
#pragma unroll 8
  for (int i = 0; i < HIDC / 4; i++) {
    float4 xi = hv[i]; float4 ww = w[i];
    acc += xi.x * ww.x + xi.y * ww.y + xi.z * ww.z + xi.w * ww.w;
  }
  red[t] = fmaxf(acc, 0.0f) * Wr[t];
  __syncthreads();
#pragma unroll
  for (int s = 128; s > 0; s >>= 1) {
    if (t < s) red[t] += red[t + s];
    __syncthreads();
  }
  if (t == 0) atomicAdd(&c[bt / 18], red[0] * (1.0f / 18.0f));
}

__global__ void final_kernel(const float* __restrict__ c, const float* __restrict__ br,
                             float* __restrict__ out) {
  int b = threadIdx.x;
  if (b < BGR) out[b] = 1.0f / (1.0f + expf(-(c[b] + br[0])));
}

extern "C" void kernel_launch(void* const* d_in, const int* in_sizes, int n_in,
                              void* d_out, int out_size, void* d_ws, size_t ws_size,
                              hipStream_t stream) {
  const float* x   = (const float*)d_in[0];
  const int*   ei  = (const int*)d_in[1];
  const float* ea  = (const float*)d_in[2];
  const float* Wq  = (const float*)d_in[4];  const float* bq  = (const float*)d_in[5];
  const float* Wk  = (const float*)d_in[6];  const float* bk  = (const float*)d_in[7];
  const float* Wv  = (const float*)d_in[8];  const float* bv  = (const float*)d_in[9];
  const float* We  = (const float*)d_in[10];
  const float* Wsk = (const float*)d_in[11]; const float* bsk = (const float*)d_in[12];
  const float* lng = (const float*)d_in[13]; const float* lnb = (const float*)d_in[14];
  const float* bng = (const float*)d_in[15]; const float* bnb = (const float*)d_in[16];
  const float* W1  = (const float*)d_in[17]; const float* b1  = (const float*)d_in[18];
  const float* Wr  = (const float*)d_in[19]; const float* br  = (const float*)d_in[20];
  float* outp = (float*)d_out;

  const int* srcArr = ei;
  const int* dstArr = ei + NEDGES;

  char* ws = (char*)d_ws;
  size_t off = 0;
  auto alloc = [&](size_t bytes) -> void* {
    void* p = ws + off;
    off += (bytes + 255) & ~(size_t)255;
    return p;
  };
  float* xln       = (float*)alloc((size_t)NNODES * INCH * 4);
  float* QKVS      = (float*)alloc((size_t)NNODES * 1024 * 4);
  float* outb      = (float*)alloc((size_t)NNODES * HIDC * 4);
  float* hbuf      = (float*)alloc((size_t)BGR * 18 * HIDC * 4);
  int*   row_start = (int*)alloc((size_t)(NNODES + 1) * 4);
  int*   elist     = (int*)alloc((size_t)NEDGES * 4);
  int*   deg       = (int*)alloc((size_t)NNODES * 4);
  int*   cursor    = (int*)alloc((size_t)NNODES * 4);
  float* sums      = (float*)alloc(HIDC * 4);
  float* sumsq     = (float*)alloc(HIDC * 4);
  float* cacc      = (float*)alloc(BGR * 4);

  // zero accumulators (workspace is poisoned with 0xAA before every launch)
  hipMemsetAsync(deg,    0, (size_t)NNODES * 4, stream);
  hipMemsetAsync(cursor, 0, (size_t)NNODES * 4, stream);
  hipMemsetAsync(sums,   0, HIDC * 4, stream);
  hipMemsetAsync(sumsq,  0, HIDC * 4, stream);
  hipMemsetAsync(cacc,   0, BGR * 4, stream);

  ln_kernel<<<NNODES / 4, 256, 0, stream>>>(x, lng, lnb, xln);
  dim3 ggrid((NNODES + BM - 1) / BM, 16);
  gemm_qkvs<<<ggrid, 256, 0, stream>>>(xln, Wq, bq, Wk, bk, Wv, bv, Wsk, bsk, QKVS);
  count_kernel<<<NEDGES / 256, 256, 0, stream>>>(dstArr, deg);
  scan_kernel<<<1, 256, 0, stream>>>(deg, row_start);
  scatter_kernel<<<NEDGES / 256, 256, 0, stream>>>(dstArr, row_start, cursor, elist);
  agg_kernel<<<NNODES / 4, 256, 0, stream>>>(QKVS, ea, We, srcArr, row_start, elist, outb);
  bnstat_kernel<<<132, 256, 0, stream>>>(outb, sums, sumsq);
  pool_kernel<<<BGR * 18, 256, 0, stream>>>(outb, sums, sumsq, bng, bnb, hbuf);
  mlp_kernel<<<BGR * 18, 256, 0, stream>>>(hbuf, W1, b1, Wr, cacc);
  final_kernel<<<1, 64, 0, stream>>>(cacc, br, outp);
}

// Round 3
// 323.200 us; speedup vs baseline: 5.8359x; 1.2848x over previous
//
#include <hip/hip_runtime.h>
#include <math.h>

#define NNODES 15840
#define NEDGES 253440
#define INCH 128
#define HIDC 256
#define BGR 48
#define GNODES 330

// ---------------- LayerNorm: one wave per node row (128 feats, 2/lane) ----------------
__global__ void ln_kernel(const float* __restrict__ x, const float* __restrict__ g,
                          const float* __restrict__ b, float* __restrict__ xln) {
  int wid = (blockIdx.x * blockDim.x + threadIdx.x) >> 6;
  int lane = threadIdx.x & 63;
  if (wid >= NNODES) return;
  float2 v = *(const float2*)(x + (size_t)wid * INCH + lane * 2);
  float s = v.x + v.y;
#pragma unroll
  for (int o = 32; o > 0; o >>= 1) s += __shfl_xor(s, o);
  float mean = s * (1.0f / INCH);
  float d0 = v.x - mean, d1 = v.y - mean;
  float sq = d0 * d0 + d1 * d1;
#pragma unroll
  for (int o = 32; o > 0; o >>= 1) sq += __shfl_xor(sq, o);
  float rstd = rsqrtf(sq * (1.0f / INCH) + 1e-5f);
  float2 gg = *(const float2*)(g + lane * 2);
  float2 bb = *(const float2*)(b + lane * 2);
  float2 o2;
  o2.x = d0 * rstd * gg.x + bb.x;
  o2.y = d1 * rstd * gg.y + bb.y;
  *(float2*)(xln + (size_t)wid * INCH + lane * 2) = o2;
}

// ---------------- Q,K,V,Skip SGEMM: 128x128 tile, 8x8 quadrant micro-tile ----------------
#define GBM 128
#define GBN 128
#define GBK 32
#define KD 128
__global__ __launch_bounds__(256) void gemm_qkvs(
    const float* __restrict__ xln,
    const float* __restrict__ Wq, const float* __restrict__ bq,
    const float* __restrict__ Wk, const float* __restrict__ bk,
    const float* __restrict__ Wv, const float* __restrict__ bv,
    const float* __restrict__ Ws, const float* __restrict__ bs,
    float* __restrict__ QKVS) {
  __shared__ float As[GBK][GBM];
  __shared__ float Bs[GBK][GBN];
  int t = threadIdx.x;
  int m0 = blockIdx.x * GBM;
  int jb = blockIdx.y;            // 0..7 -> 128-col block of [Q|K|V|S]
  const float* W; const float* bias;
  switch (jb >> 1) {
    case 0:  W = Wq; bias = bq; break;
    case 1:  W = Wk; bias = bk; break;
    case 2:  W = Wv; bias = bv; break;
    default: W = Ws; bias = bs; break;
  }
  int j0 = (jb & 1) * GBN;        // row offset inside the 256-row weight matrix

  int r = t & 127;                // staging row (A: node row, B: weight row)
  int half = t >> 7;              // which 16-k chunk
  int tx = t & 15, ty = t >> 4;   // 16x16 thread grid

  int gr = m0 + r;
  bool okA = gr < NNODES;
  const float* arow = xln + (size_t)gr * KD;
  const float* brow = W + (size_t)(j0 + r) * KD;

  float acc[8][8] = {};

  for (int k0 = 0; k0 < KD; k0 += GBK) {
#pragma unroll
    for (int i = 0; i < 4; i++) {
      int lk = half * 16 + i * 4;
      int kc = k0 + lk;
      float4 av = okA ? *(const float4*)(arow + kc) : make_float4(0.f, 0.f, 0.f, 0.f);
      As[lk + 0][r] = av.x; As[lk + 1][r] = av.y;
      As[lk + 2][r] = av.z; As[lk + 3][r] = av.w;
      float4 bvv = *(const float4*)(brow + kc);
      Bs[lk + 0][r] = bvv.x; Bs[lk + 1][r] = bvv.y;
      Bs[lk + 2][r] = bvv.z; Bs[lk + 3][r] = bvv.w;
    }
    __syncthreads();
#pragma unroll 2
    for (int k = 0; k < GBK; k++) {
      float4 a0 = *(const float4*)&As[k][ty * 4];
      float4 a1 = *(const float4*)&As[k][64 + ty * 4];
      float4 b0 = *(const float4*)&Bs[k][tx * 4];
      float4 b1 = *(const float4*)&Bs[k][64 + tx * 4];
      float aa[8] = {a0.x, a0.y, a0.z, a0.w, a1.x, a1.y, a1.z, a1.w};
      float bb[8] = {b0.x, b0.y, b0.z, b0.w, b1.x, b1.y, b1.z, b1.w};
#pragma unroll
      for (int ar = 0; ar < 8; ar++)
#pragma unroll
        for (int ac = 0; ac < 8; ac++) acc[ar][ac] += aa[ar] * bb[ac];
    }
    __syncthreads();
  }

  float4 bb0 = *(const float4*)(bias + j0 + tx * 4);
  float4 bb1 = *(const float4*)(bias + j0 + 64 + tx * 4);
  int col0 = jb * 128 + tx * 4;
#pragma unroll
  for (int ar = 0; ar < 8; ar++) {
    int grow = m0 + ((ar < 4) ? (ty * 4 + ar) : (64 + ty * 4 + ar - 4));
    if (grow < NNODES) {
      float4 o0, o1;
      o0.x = acc[ar][0] + bb0.x; o0.y = acc[ar][1] + bb0.y;
      o0.z = acc[ar][2] + bb0.z; o0.w = acc[ar][3] + bb0.w;
      o1.x = acc[ar][4] + bb1.x; o1.y = acc[ar][5] + bb1.y;
      o1.z = acc[ar][6] + bb1.z; o1.w = acc[ar][7] + bb1.w;
      *(float4*)(QKVS + (size_t)grow * 1024 + col0) = o0;
      *(float4*)(QKVS + (size_t)grow * 1024 + col0 + 64) = o1;
    }
  }
}

// ---------------- CSR build ----------------
__global__ void count_kernel(const int* __restrict__ dst, int* __restrict__ deg) {
  int e = blockIdx.x * blockDim.x + threadIdx.x;
  if (e < NEDGES) atomicAdd(&deg[dst[e]], 1);
}

// 1024-thread single-block shfl scan
__global__ void scan_kernel(const int* __restrict__ deg, int* __restrict__ row_start) {
  __shared__ int wsum[16];
  __shared__ int carry_s;
  int t = threadIdx.x;
  int lane = t & 63, w = t >> 6;
  if (t == 0) carry_s = 0;
  __syncthreads();
  for (int base = 0; base < NNODES; base += 1024) {
    int i = base + t;
    int v = (i < NNODES) ? deg[i] : 0;
    int inc = v;
#pragma unroll
    for (int o = 1; o < 64; o <<= 1) {
      int nv = __shfl_up(inc, o);
      if (lane >= o) inc += nv;
    }
    if (lane == 63) wsum[w] = inc;
    __syncthreads();
    if (w == 0 && lane < 16) {
      int ws = wsum[lane];
#pragma unroll
      for (int o = 1; o < 16; o <<= 1) {
        int nv = __shfl_up(ws, o);
        if (lane >= o) ws += nv;
      }
      wsum[lane] = ws;
    }
    __syncthreads();
    int wexcl = (w > 0) ? wsum[w - 1] : 0;
    int chunk_total = wsum[15];
    int cl = carry_s;
    if (i < NNODES) row_start[i] = cl + wexcl + inc - v;
    __syncthreads();
    if (t == 0) carry_s += chunk_total;
  }
  __syncthreads();
  if (t == 0) row_start[NNODES] = carry_s;
}

__global__ void scatter_kernel(const int* __restrict__ dst, const int* __restrict__ row_start,
                               int* __restrict__ cursor, int* __restrict__ elist) {
  int e = blockIdx.x * blockDim.x + threadIdx.x;
  if (e < NEDGES) {
    int d = dst[e];
    int pos = atomicAdd(&cursor[d], 1);
    elist[row_start[d] + pos] = e;
  }
}

// ---------------- Attention: one wave/dst, factored edge algebra, 4-edge batches ---------
__global__ __launch_bounds__(256) void agg_kernel(
    const float* __restrict__ QKVS, const float* __restrict__ edge_attr,
    const float* __restrict__ We, const int* __restrict__ srcArr,
    const int* __restrict__ row_start, const int* __restrict__ elist,
    float* __restrict__ outb) {
  int t = threadIdx.x;
  int nd = blockIdx.x * 4 + (t >> 6);
  int lane = t & 63;
  if (nd >= NNODES) return;

  // per-lane We fragment: rows 4*lane..4*lane+3 (feature dim), 5 cols
  float wp[4][5];
#pragma unroll
  for (int c = 0; c < 4; c++)
#pragma unroll
    for (int d = 0; d < 5; d++) wp[c][d] = We[(4 * lane + c) * 5 + d];

  float4 q = *(const float4*)(QKVS + (size_t)nd * 1024 + 4 * lane);

  // c5 = We^T q  (5-vector, replicated on all lanes)
  float c5[5];
#pragma unroll
  for (int d = 0; d < 5; d++) {
    float s = q.x * wp[0][d] + q.y * wp[1][d] + q.z * wp[2][d] + q.w * wp[3][d];
#pragma unroll
    for (int o = 32; o > 0; o >>= 1) s += __shfl_xor(s, o);
    c5[d] = s;
  }

  int beg = row_start[nd], end = row_start[nd + 1];
  float m = -INFINITY, z = 0.0f;
  float ax = 0.f, ay = 0.f, az = 0.f, aw = 0.f;
  float ea_acc[5] = {0.f, 0.f, 0.f, 0.f, 0.f};

  int j = beg;
  for (; j + 4 <= end; j += 4) {
    int e0 = elist[j], e1 = elist[j + 1], e2 = elist[j + 2], e3 = elist[j + 3];
    int s0 = srcArr[e0], s1 = srcArr[e1], s2 = srcArr[e2], s3 = srcArr[e3];
    const float* b0 = QKVS + (size_t)s0 * 1024 + 4 * lane;
    const float* b1 = QKVS + (size_t)s1 * 1024 + 4 * lane;
    const float* b2 = QKVS + (size_t)s2 * 1024 + 4 * lane;
    const float* b3 = QKVS + (size_t)s3 * 1024 + 4 * lane;
    float4 k0 = *(const float4*)(b0 + 256);
    float4 k1 = *(const float4*)(b1 + 256);
    float4 k2 = *(const float4*)(b2 + 256);
    float4 k3 = *(const float4*)(b3 + 256);
    float4 v0 = *(const float4*)(b0 + 512);
    float4 v1 = *(const float4*)(b1 + 512);
    float4 v2 = *(const float4*)(b2 + 512);
    float4 v3 = *(const float4*)(b3 + 512);
    float eat[4][5];
#pragma unroll
    for (int d = 0; d < 5; d++) {
      eat[0][d] = edge_attr[(size_t)e0 * 5 + d];
      eat[1][d] = edge_attr[(size_t)e1 * 5 + d];
      eat[2][d] = edge_attr[(size_t)e2 * 5 + d];
      eat[3][d] = edge_attr[(size_t)e3 * 5 + d];
    }
    float p0 = q.x * k0.x + q.y * k0.y + q.z * k0.z + q.w * k0.w;
    float p1 = q.x * k1.x + q.y * k1.y + q.z * k1.z + q.w * k1.w;
    float p2 = q.x * k2.x + q.y * k2.y + q.z * k2.z + q.w * k2.w;
    float p3 = q.x * k3.x + q.y * k3.y + q.z * k3.z + q.w * k3.w;
#pragma unroll
    for (int o = 32; o > 0; o >>= 1) {
      p0 += __shfl_xor(p0, o); p1 += __shfl_xor(p1, o);
      p2 += __shfl_xor(p2, o); p3 += __shfl_xor(p3, o);
    }
    float dt0 = 0.f, dt1 = 0.f, dt2 = 0.f, dt3 = 0.f;
#pragma unroll
    for (int d = 0; d < 5; d++) {
      dt0 += c5[d] * eat[0][d]; dt1 += c5[d] * eat[1][d];
      dt2 += c5[d] * eat[2][d]; dt3 += c5[d] * eat[3][d];
    }
    float al0 = (p0 + dt0) * 0.0625f, al1 = (p1 + dt1) * 0.0625f;
    float al2 = (p2 + dt2) * 0.0625f, al3 = (p3 + dt3) * 0.0625f;
    float bm = fmaxf(fmaxf(al0, al1), fmaxf(al2, al3));
    float nm = fmaxf(m, bm);
    float sc = __expf(m - nm);
    float w0 = __expf(al0 - nm), w1 = __expf(al1 - nm);
    float w2 = __expf(al2 - nm), w3 = __expf(al3 - nm);
    z = z * sc + (w0 + w1 + w2 + w3);
    ax = ax * sc + w0 * v0.x + w1 * v1.x + w2 * v2.x + w3 * v3.x;
    ay = ay * sc + w0 * v0.y + w1 * v1.y + w2 * v2.y + w3 * v3.y;
    az = az * sc + w0 * v0.z + w1 * v1.z + w2 * v2.z + w3 * v3.z;
    aw = aw * sc + w0 * v0.w + w1 * v1.w + w2 * v2.w + w3 * v3.w;
#pragma unroll
    for (int d = 0; d < 5; d++)
      ea_acc[d] = ea_acc[d] * sc + w0 * eat[0][d] + w1 * eat[1][d] + w2 * eat[2][d] + w3 * eat[3][d];
    m = nm;
  }
  for (; j < end; j++) {
    int e = elist[j];
    int s = srcArr[e];
    const float* bp = QKVS + (size_t)s * 1024 + 4 * lane;
    float4 k4 = *(const float4*)(bp + 256);
    float4 v4 = *(const float4*)(bp + 512);
    float eat[5];
#pragma unroll
    for (int d = 0; d < 5; d++) eat[d] = edge_attr[(size_t)e * 5 + d];
    float p = q.x * k4.x + q.y * k4.y + q.z * k4.z + q.w * k4.w;
#pragma unroll
    for (int o = 32; o > 0; o >>= 1) p += __shfl_xor(p, o);
    float dt = 0.f;
#pragma unroll
    for (int d = 0; d < 5; d++) dt += c5[d] * eat[d];
    float al = (p + dt) * 0.0625f;
    float nm = fmaxf(m, al);
    float sc = __expf(m - nm);
    float w = __expf(al - nm);
    z = z * sc + w;
    ax = ax * sc + w * v4.x; ay = ay * sc + w * v4.y;
    az = az * sc + w * v4.z; aw = aw * sc + w * v4.w;
#pragma unroll
    for (int d = 0; d < 5; d++) ea_acc[d] = ea_acc[d] * sc + w * eat[d];
    m = nm;
  }

  float inv = 1.0f / (z + 1e-16f);
  float4 sk = *(const float4*)(QKVS + (size_t)nd * 1024 + 768 + 4 * lane);
  float efx = 0.f, efy = 0.f, efz = 0.f, efw = 0.f;
#pragma unroll
  for (int d = 0; d < 5; d++) {
    efx += wp[0][d] * ea_acc[d]; efy += wp[1][d] * ea_acc[d];
    efz += wp[2][d] * ea_acc[d]; efw += wp[3][d] * ea_acc[d];
  }
  float4 o;
  o.x = (ax + efx) * inv + sk.x;
  o.y = (ay + efy) * inv + sk.y;
  o.z = (az + efz) * inv + sk.z;
  o.w = (aw + efw) * inv + sk.w;
  *(float4*)(outb + (size_t)nd * HIDC + 4 * lane) = o;
}

// ---------------- BatchNorm statistics ----------------
__global__ void bnstat_kernel(const float* __restrict__ outb, float* __restrict__ sums,
                              float* __restrict__ sumsq) {
  int f = threadIdx.x;
  int r0 = blockIdx.x * 120;
  float s = 0.0f, sq = 0.0f;
  for (int r = 0; r < 120; r++) {
    float v = outb[(size_t)(r0 + r) * HIDC + f];
    s += v; sq += v * v;
  }
  atomicAdd(&sums[f], s);
  atomicAdd(&sumsq[f], sq);
}

// ---------------- BN-apply + ReLU + max-pool + MLP head, fused ----------------
__global__ void pool_mlp_kernel(const float* __restrict__ outb, const float* __restrict__ sums,
                                const float* __restrict__ sumsq, const float* __restrict__ bng,
                                const float* __restrict__ bnb, const float* __restrict__ W1,
                                const float* __restrict__ b1, const float* __restrict__ Wr,
                                float* __restrict__ c) {
  __shared__ float hs[HIDC];
  __shared__ float red[HIDC];
  int bt = blockIdx.x, t = threadIdx.x;
  int b = bt / 18, tt = bt % 18;
  float mean = sums[t] * (1.0f / NNODES);
  float var = sumsq[t] * (1.0f / NNODES) - mean * mean;
  float scale = bng[t] * rsqrtf(var + 1e-5f);
  float shift = bnb[t] - mean * scale;
  int base = b * GNODES + tt * 18;
  float mx = -INFINITY;
  for (int r = 0; r < 18; r++) {
    float v = outb[(size_t)(base + r) * HIDC + t];
    mx = fmaxf(mx, fmaxf(v * scale + shift, 0.0f));
  }
  hs[t] = mx;
  __syncthreads();
  const float4* hv = (const float4*)hs;
  const float4* w = (const float4*)(W1 + t * HIDC);
  float acc = b1[t];
#pragma unroll 8
  for (int i = 0; i < HIDC / 4; i++) {
    float4 xi = hv[i]; float4 ww = w[i];
    acc += xi.x * ww.x + xi.y * ww.y + xi.z * ww.z + xi.w * ww.w;
  }
  red[t] = fmaxf(acc, 0.0f) * Wr[t];
  __syncthreads();
#pragma unroll
  for (int s = 128; s > 0; s >>= 1) {
    if (t < s) red[t] += red[t + s];
    __syncthreads();
  }
  if (t == 0) atomicAdd(&c[b], red[0] * (1.0f / 18.0f));
}

__global__ void final_kernel(const float* __restrict__ c, const float* __restrict__ br,
                             float* __restrict__ out) {
  int b = threadIdx.x;
  if (b < BGR) out[b] = 1.0f / (1.0f + expf(-(c[b] + br[0])));
}

extern "C" void kernel_launch(void* const* d_in, const int* in_sizes, int n_in,
                              void* d_out, int out_size, void* d_ws, size_t ws_size,
                              hipStream_t stream) {
  const float* x   = (const float*)d_in[0];
  const int*   ei  = (const int*)d_in[1];
  const float* ea  = (const float*)d_in[2];
  const float* Wq  = (const float*)d_in[4];  const float* bq  = (const float*)d_in[5];
  const float* Wk  = (const float*)d_in[6];  const float* bk  = (const float*)d_in[7];
  const float* Wv  = (const float*)d_in[8];  const float* bv  = (const float*)d_in[9];
  const float* We  = (const float*)d_in[10];
  const float* Wsk = (const float*)d_in[11]; const float* bsk = (const float*)d_in[12];
  const float* lng = (const float*)d_in[13]; const float* lnb = (const float*)d_in[14];
  const float* bng = (const float*)d_in[15]; const float* bnb = (const float*)d_in[16];
  const float* W1  = (const float*)d_in[17]; const float* b1  = (const float*)d_in[18];
  const float* Wr  = (const float*)d_in[19]; const float* br  = (const float*)d_in[20];
  float* outp = (float*)d_out;

  const int* srcArr = ei;
  const int* dstArr = ei + NEDGES;

  char* ws = (char*)d_ws;
  size_t off = 0;
  auto alloc = [&](size_t bytes) -> void* {
    void* p = ws + off;
    off += (bytes + 255) & ~(size_t)255;
    return p;
  };
  float* xln       = (float*)alloc((size_t)NNODES * INCH * 4);
  float* QKVS      = (float*)alloc((size_t)NNODES * 1024 * 4);
  float* outb      = (float*)alloc((size_t)NNODES * HIDC * 4);
  int*   row_start = (int*)alloc((size_t)(NNODES + 1) * 4);
  int*   elist     = (int*)alloc((size_t)NEDGES * 4);
  // contiguous zero block: deg, cursor, sums, sumsq, cacc
  size_t zn = (size_t)NNODES * 2 + HIDC * 2 + BGR;
  int* zblock = (int*)alloc(zn * 4);
  int*   deg    = zblock;
  int*   cursor = zblock + NNODES;
  float* sums   = (float*)(zblock + 2 * NNODES);
  float* sumsq  = sums + HIDC;
  float* cacc   = sumsq + HIDC;

  hipMemsetAsync(zblock, 0, zn * 4, stream);

  ln_kernel<<<NNODES / 4, 256, 0, stream>>>(x, lng, lnb, xln);
  dim3 ggrid((NNODES + GBM - 1) / GBM, 8);
  gemm_qkvs<<<ggrid, 256, 0, stream>>>(xln, Wq, bq, Wk, bk, Wv, bv, Wsk, bsk, QKVS);
  count_kernel<<<NEDGES / 256, 256, 0, stream>>>(dstArr, deg);
  scan_kernel<<<1, 1024, 0, stream>>>(deg, row_start);
  scatter_kernel<<<NEDGES / 256, 256, 0, stream>>>(dstArr, row_start, cursor, elist);
  agg_kernel<<<NNODES / 4, 256, 0, stream>>>(QKVS, ea, We, srcArr, row_start, elist, outb);
  bnstat_kernel<<<132, 256, 0, stream>>>(outb, sums, sumsq);
  pool_mlp_kernel<<<BGR * 18, 256, 0, stream>>>(outb, sums, sumsq, bng, bnb, W1, b1, Wr, cacc);
  final_kernel<<<1, 64, 0, stream>>>(cacc, br, outp);
}